// Round 1
// baseline (195.725 us; speedup 1.0000x reference)
//
#include <hip/hip_runtime.h>
#include <math.h>

#define DIMH 256        // D
#define NB   32         // batch
#define E_TOT 43234
#define TE   32         // entities per block (1352 blocks, e-split = traffic-free)
#define DK   32         // d-chunk staged in LDS
#define NC   (DIMH / DK)  // 8 chunks

typedef float v2f __attribute__((ext_vector_type(2)));
typedef float v4f __attribute__((ext_vector_type(4)));

// Kernel 1: rotate head by relation phase, emit interleaved (re0,re1,im0,im1)
// float4 per (b, dpair). sincos via HW trans unit in REVOLUTIONS:
// phase_rad = rel * (PI/0.03125)  =>  rev = phase/(2*PI) = rel * 16 exactly.
// fract() is the exact range reduction v_sin_f32/v_cos_f32 need.
__global__ __launch_bounds__(64) void rot_kernel(const float* __restrict__ head,
                                                 const float* __restrict__ rel,
                                                 float4* __restrict__ rot_v4) {
    int i  = blockIdx.x * 64 + threadIdx.x;   // 0..4095
    int b  = i >> 7;
    int dp = i & 127;
    int d0 = dp * 2;
    float4 w;
    {
        float re_h = head[b * 2 * DIMH + d0];
        float im_h = head[b * 2 * DIMH + DIMH + d0];
        float x = rel[b * DIMH + d0] * 16.0f;       // revolutions
        float f = x - floorf(x);
        float s = __builtin_amdgcn_sinf(f);
        float c = __builtin_amdgcn_cosf(f);
        w.x = re_h * c - im_h * s;
        w.z = re_h * s + im_h * c;
    }
    {
        float re_h = head[b * 2 * DIMH + d0 + 1];
        float im_h = head[b * 2 * DIMH + DIMH + d0 + 1];
        float x = rel[b * DIMH + d0 + 1] * 16.0f;
        float f = x - floorf(x);
        float s = __builtin_amdgcn_sinf(f);
        float c = __builtin_amdgcn_cosf(f);
        w.y = re_h * c - im_h * s;
        w.w = re_h * s + im_h * c;
    }
    rot_v4[b * (DIMH / 2) + dp] = w;
}

__device__ __forceinline__ v2f sqrt2(v2f s) {
    v2f r;
    r.x = __builtin_amdgcn_sqrtf(s.x);
    r.y = __builtin_amdgcn_sqrtf(s.y);
    return r;
}

// Kernel 2: 1-wave blocks (64 thr), TE=32 entities x all 32 batches.
// 4x4 register tile per thread (bg = tid>>3 -> batches 4bg..4bg+3,
// eg = tid&7 -> entities 4eg..4eg+3): 8 ds_read_b128 feed 32 element-
// contribs = 4 B/elem LDS (was 8) -> VALU-bound instead of LDS-pipe-bound
// (prev round: VALUBusy 53.5% == 26/48 LDS:VALU ratio, LDS-bound).
// Single wave => no __syncthreads anywhere; chunk double-buffer via regs
// is ordered by the in-order DS pipe.
// LDS: [32][16] v4f (256 B rows), XOR swizzle col' = p ^ (row>>2):
// for every p the 8 distinct wave addresses hit 8 disjoint 4-bank spans
// (verified by enumeration: parity argument kills all collisions);
// r-reads broadcast over the 8 lanes sharing bg. Stores land uniformly
// 8-deep per bank = the b128 minimum.
__global__ __launch_bounds__(64, 2) void dist_kernel(const float* __restrict__ ent,
                                                     const float4* __restrict__ rot_v4,
                                                     float* __restrict__ out) {
    __shared__ v4f s_e[TE][16];   // 8 KB
    __shared__ v4f s_r[NB][16];   // 8 KB

    const int tid = threadIdx.x;       // 0..63
    const int eb  = blockIdx.x * TE;
    const int eg  = tid & 7;           // entity group
    const int bg  = tid >> 3;          // batch group

    // staging task decomposition (64 threads):
    // ent: 32 rows x 8 quads = 256 tasks -> 4/thread (rows erow+8k, quad eq)
    // rot: 32 rows x 16 cols = 512 v4f  -> 8/thread (rows rrow+4k, col rcol)
    const int erow = tid >> 3;
    const int eq   = tid & 7;
    const int rrow = tid >> 4;
    const int rcol = tid & 15;

    float4 pe_re[4], pe_im[4], pr[8];

    auto load_chunk = [&](int c) {
        const int dk = c * DK;
        #pragma unroll
        for (int k = 0; k < 4; ++k) {
            int er = min(eb + 8 * k + erow, E_TOT - 1);
            const float* b0 = ent + (size_t)er * (2 * DIMH);
            pe_re[k] = *reinterpret_cast<const float4*>(b0 + dk + 4 * eq);
            pe_im[k] = *reinterpret_cast<const float4*>(b0 + DIMH + dk + 4 * eq);
        }
        #pragma unroll
        for (int k = 0; k < 8; ++k)
            pr[k] = rot_v4[(4 * k + rrow) * (DIMH / 2) + c * (DK / 2) + rcol];
    };

    auto store_chunk = [&]() {
        #pragma unroll
        for (int k = 0; k < 4; ++k) {
            int row = 8 * k + erow;
            int s = (row >> 2) & 7;
            v4f lo, hi;
            lo.x = pe_re[k].x; lo.y = pe_re[k].y; lo.z = pe_im[k].x; lo.w = pe_im[k].y;
            hi.x = pe_re[k].z; hi.y = pe_re[k].w; hi.z = pe_im[k].z; hi.w = pe_im[k].w;
            s_e[row][(2 * eq)     ^ s] = lo;
            s_e[row][(2 * eq + 1) ^ s] = hi;
        }
        #pragma unroll
        for (int k = 0; k < 8; ++k) {
            int row = 4 * k + rrow;
            int s = (row >> 2) & 7;
            v4f r; r.x = pr[k].x; r.y = pr[k].y; r.z = pr[k].z; r.w = pr[k].w;
            s_r[row][rcol ^ s] = r;
        }
    };

    v2f acc[4][4];   // [batch j][entity k] — static indices only (no scratch)
    #pragma unroll
    for (int j = 0; j < 4; ++j)
        #pragma unroll
        for (int k = 0; k < 4; ++k) { acc[j][k].x = 0.f; acc[j][k].y = 0.f; }

    load_chunk(0);

    #pragma unroll 1
    for (int c = 0; c < NC; ++c) {
        store_chunk();                       // regs (chunk c) -> LDS
        if (c + 1 < NC) load_chunk(c + 1);   // prefetch next chunk under compute

        #pragma unroll 4
        for (int p = 0; p < DK / 2; ++p) {
            v4f r0 = s_r[4 * bg + 0][p ^ bg];
            v4f r1 = s_r[4 * bg + 1][p ^ bg];
            v4f r2 = s_r[4 * bg + 2][p ^ bg];
            v4f r3 = s_r[4 * bg + 3][p ^ bg];
            v4f e0 = s_e[4 * eg + 0][p ^ eg];
            v4f e1 = s_e[4 * eg + 1][p ^ eg];
            v4f e2 = s_e[4 * eg + 2][p ^ eg];
            v4f e3 = s_e[4 * eg + 3][p ^ eg];
            #define CONTRIB(J, K, R, E)                         \
                { v2f a = R.xy - E.xy; v2f b = R.zw - E.zw;     \
                  acc[J][K] += sqrt2(a * a + b * b); }
            CONTRIB(0,0,r0,e0) CONTRIB(0,1,r0,e1) CONTRIB(0,2,r0,e2) CONTRIB(0,3,r0,e3)
            CONTRIB(1,0,r1,e0) CONTRIB(1,1,r1,e1) CONTRIB(1,2,r1,e2) CONTRIB(1,3,r1,e3)
            CONTRIB(2,0,r2,e0) CONTRIB(2,1,r2,e1) CONTRIB(2,2,r2,e2) CONTRIB(2,3,r2,e3)
            CONTRIB(3,0,r3,e0) CONTRIB(3,1,r3,e1) CONTRIB(3,2,r3,e2) CONTRIB(3,3,r3,e3)
            #undef CONTRIB
        }
    }

    // epilogue: 4 contiguous entities per (thread, batch) -> float2 pairs.
    // NOTE: out rows are b*43234 floats -> only 8 B aligned (43234*4 % 16 != 0),
    // so float2 is the widest legal store. Lanes sharing bg cover contiguous
    // 128 B spans per batch row.
    #pragma unroll
    for (int j = 0; j < 4; ++j) {
        int b = 4 * bg + j;
        float v0 = 6.0f - (acc[j][0].x + acc[j][0].y);
        float v1 = 6.0f - (acc[j][1].x + acc[j][1].y);
        float v2 = 6.0f - (acc[j][2].x + acc[j][2].y);
        float v3 = 6.0f - (acc[j][3].x + acc[j][3].y);
        int e4 = eb + 4 * eg;
        float* op = out + (size_t)b * E_TOT + e4;
        if (e4 + 3 < E_TOT) {
            float2 w0; w0.x = v0; w0.y = v1;
            float2 w1; w1.x = v2; w1.y = v3;
            *reinterpret_cast<float2*>(op)     = w0;
            *reinterpret_cast<float2*>(op + 2) = w1;
        } else {
            if (e4     < E_TOT) op[0] = v0;
            if (e4 + 1 < E_TOT) op[1] = v1;
            if (e4 + 2 < E_TOT) op[2] = v2;
            if (e4 + 3 < E_TOT) op[3] = v3;
        }
    }
}

extern "C" void kernel_launch(void* const* d_in, const int* in_sizes, int n_in,
                              void* d_out, int out_size, void* d_ws, size_t ws_size,
                              hipStream_t stream) {
    const float* head = (const float*)d_in[0];   // (32, 512)
    const float* rel  = (const float*)d_in[1];   // (32, 256)
    const float* ent  = (const float*)d_in[2];   // (43234, 512)
    float4* rot_v4 = (float4*)d_ws;              // 32 * 128 * 16 B = 64 KB

    rot_kernel<<<(NB * DIMH / 2) / 64, 64, 0, stream>>>(head, rel, rot_v4);

    int etiles = (E_TOT + TE - 1) / TE;          // 1352
    dist_kernel<<<etiles, 64, 0, stream>>>(ent, rot_v4, (float*)d_out);
}